// Round 8
// baseline (324.841 us; speedup 1.0000x reference)
//
#include <hip/hip_runtime.h>

#define N_NODES 50000
#define N_PAD   50048                    // padded rows (multiple of 64)
#define N_EDGES 800000
#define N_GRAPHS 256
#define D 128
#define CAP 64                           // fixed CSR row capacity (max in-degree ~40 for this dataset)
#define GEMM_GRID (N_PAD / 64)           // 782

typedef short bf16x8 __attribute__((ext_vector_type(8)));
typedef float f32x4  __attribute__((ext_vector_type(4)));

// bf16 helpers (bit-exact RNE convert)
__device__ inline unsigned short f2bf(float f) {
    unsigned u = __float_as_uint(f);
    u += 0x7FFF + ((u >> 16) & 1);
    return (unsigned short)(u >> 16);
}
__device__ inline float bf2f(unsigned short b) { return __uint_as_float((unsigned)b << 16); }

// ---------------- W pack: per-MFMA-fragment contiguous, hi/lo bf16 split ----------------
// layer layout: [frag f=(kt*8+nt)][lane][8] hi plane (16384 us), then lo plane (16384 us)
__global__ __launch_bounds__(256) void k_pack(const float* __restrict__ W1, const float* __restrict__ W2,
                                              const float* __restrict__ W3, unsigned short* __restrict__ Wp) {
    int idx = blockIdx.x * 256 + threadIdx.x;        // 3*16384
    if (idx >= 3 * D * D) return;
    int L = idx >> 14, rem = idx & 16383;
    int k = rem >> 7, n = rem & 127;
    const float* W = (L == 0) ? W1 : (L == 1) ? W2 : W3;
    float w = W[k * D + n];
    int kt = k >> 5, kg = (k >> 3) & 3, i = k & 7;
    int nt = n >> 4, ln = kg * 16 + (n & 15);
    size_t dst = (size_t)L * 32768 + ((size_t)(kt * 8 + nt) * 64 + ln) * 8 + i;
    unsigned short hi = f2bf(w);
    Wp[dst]         = hi;
    Wp[dst + 16384] = f2bf(w - bf2f(hi));            // residual
}

// ---------------- CSR build: XCD-exclusive dst ownership ----------------
// 8 groups (g = blockIdx&7 -> XCD g, round-robin dispatch heuristic); the 32 blocks of each
// group scan the whole edge list coalesced and keep edges with h(dst)==g, h(d)=(d>>4)&7.
// cnt lines (16 nodes) and col lines are then written by a single XCD -> stores merge in its
// L2 instead of ping-ponging partial lines across 8 non-coherent L2s (R7: 49MB write-back).
// Correct regardless of the actual block->XCD mapping (filter is exhaustive + exclusive).

#define SLICE_I4 (N_EDGES / 32 / 4)      // 6250 int4 per slice

__global__ __launch_bounds__(256) void k_fill(const int* __restrict__ ei, int* __restrict__ cnt,
                                              int* __restrict__ col) {
    const int g = blockIdx.x & 7;
    const int s = blockIdx.x >> 3;       // slice 0..31
    const int4* src4 = reinterpret_cast<const int4*>(ei) + (size_t)s * SLICE_I4;
    const int4* dst4 = reinterpret_cast<const int4*>(ei + N_EDGES) + (size_t)s * SLICE_I4;
    for (int i = threadIdx.x; i < SLICE_I4; i += 256) {
        int4 d = dst4[i];
        int4 sc = src4[i];
        if (((d.x >> 4) & 7) == g) { int p = atomicAdd(&cnt[d.x], 1); if (p < CAP) col[d.x * CAP + p] = sc.x; }
        if (((d.y >> 4) & 7) == g) { int p = atomicAdd(&cnt[d.y], 1); if (p < CAP) col[d.y * CAP + p] = sc.y; }
        if (((d.z >> 4) & 7) == g) { int p = atomicAdd(&cnt[d.z], 1); if (p < CAP) col[d.z * CAP + p] = sc.z; }
        if (((d.w >> 4) & 7) == g) { int p = atomicAdd(&cnt[d.w], 1); if (p < CAP) col[d.w * CAP + p] = sc.w; }
    }
}

// ---------------- MFMA GEMM: T'(bf16) = dinv_row * (A @ W)  (W hi/lo split, no LDS) ----------------
// wave = 16 rows x 128 cols; A-frag b128 direct from global

template<bool F32IN>
__global__ __launch_bounds__(256) void k_mfma(const void* __restrict__ Ain,
                                              const unsigned short* __restrict__ Wp,
                                              const int* __restrict__ cnt,
                                              unsigned short* __restrict__ T) {
    int l  = threadIdx.x & 63;
    int wv = threadIdx.x >> 6;
    int row0 = blockIdx.x * 64 + wv * 16;
    int arow = row0 + (l & 15);
    int kchunk = l >> 4;
    const uint4* wp4 = reinterpret_cast<const uint4*>(Wp);   // [frag*64+lane], lo at +2048

    f32x4 acc[8] = {};
    #pragma unroll
    for (int s = 0; s < 4; ++s) {                    // K steps of 32
        bf16x8 af;
        if (F32IN) {
            float4 a0 = {}, a1 = {};
            if (arow < N_NODES) {
                const float* xr = (const float*)Ain + (size_t)arow * D + s * 32 + kchunk * 8;
                a0 = reinterpret_cast<const float4*>(xr)[0];
                a1 = reinterpret_cast<const float4*>(xr)[1];
            }
            unsigned short h[8] = { f2bf(a0.x), f2bf(a0.y), f2bf(a0.z), f2bf(a0.w),
                                    f2bf(a1.x), f2bf(a1.y), f2bf(a1.z), f2bf(a1.w) };
            __builtin_memcpy(&af, h, 16);
        } else {
            const unsigned short* ar = (const unsigned short*)Ain + (size_t)arow * D;
            uint4 av = reinterpret_cast<const uint4*>(ar)[s * 4 + kchunk];
            __builtin_memcpy(&af, &av, 16);
        }
        #pragma unroll
        for (int nt = 0; nt < 8; ++nt) {
            int f = s * 8 + nt;
            uint4 bh = wp4[f * 64 + l];
            uint4 bl = wp4[f * 64 + l + 2048];
            bf16x8 bhf, blf;
            __builtin_memcpy(&bhf, &bh, 16);
            __builtin_memcpy(&blf, &bl, 16);
            acc[nt] = __builtin_amdgcn_mfma_f32_16x16x32_bf16(af, bhf, acc[nt], 0, 0, 0);
            acc[nt] = __builtin_amdgcn_mfma_f32_16x16x32_bf16(af, blf, acc[nt], 0, 0, 0);
        }
    }

    // C/D: col = lane&15, row = (lane>>4)*4 + reg   [m89-verified]
    int rbase = row0 + (l >> 4) * 4;
    int cr = l & 15;
    float sc[4];
    #pragma unroll
    for (int j = 0; j < 4; ++j) {
        int rr = rbase + j;
        sc[j] = (rr < N_NODES) ? rsqrtf((float)cnt[rr] + 1.f) : 0.f;   // dinv_row
    }
    #pragma unroll
    for (int nt = 0; nt < 8; ++nt)
        #pragma unroll
        for (int j = 0; j < 4; ++j) {
            int rr = rbase + j;
            if (rr < N_NODES) T[(size_t)rr * D + nt * 16 + cr] = f2bf(acc[nt][j] * sc[j]);
        }
}

// ---------------- pull aggregation: AGG[d] = dinv_d * (T'[d] + sum T'[col]) ----------------
// one wave per node; unweighted bf16-row sum, f32 accumulate

template<bool LAST>
__global__ __launch_bounds__(256) void k_agg(const unsigned* __restrict__ Tu, float* __restrict__ AGG,
                                             unsigned* __restrict__ Anext, const float* __restrict__ bias,
                                             const int* __restrict__ cnt, const int* __restrict__ col) {
    int node = blockIdx.x * 4 + (threadIdx.x >> 6);
    int lane = threadIdx.x & 63;
    if (node >= N_NODES) return;

    int len = cnt[node];
    float dd = rsqrtf((float)len + 1.f);
    unsigned ts = Tu[(size_t)node * 64 + lane];
    float2 acc;
    acc.x = __uint_as_float(ts << 16);               // low bf16 = even col
    acc.y = __uint_as_float(ts & 0xFFFF0000u);       // high bf16 = odd col

    const int* crow = col + node * CAP;              // 256B-aligned contiguous row
    int j = 0;
    for (; j + 4 <= len; j += 4) {
        int4 c = *reinterpret_cast<const int4*>(crow + j);
        unsigned t0 = Tu[(size_t)c.x * 64 + lane];
        unsigned t1 = Tu[(size_t)c.y * 64 + lane];
        unsigned t2 = Tu[(size_t)c.z * 64 + lane];
        unsigned t3 = Tu[(size_t)c.w * 64 + lane];
        acc.x += __uint_as_float(t0 << 16); acc.y += __uint_as_float(t0 & 0xFFFF0000u);
        acc.x += __uint_as_float(t1 << 16); acc.y += __uint_as_float(t1 & 0xFFFF0000u);
        acc.x += __uint_as_float(t2 << 16); acc.y += __uint_as_float(t2 & 0xFFFF0000u);
        acc.x += __uint_as_float(t3 << 16); acc.y += __uint_as_float(t3 & 0xFFFF0000u);
    }
    for (; j < len; ++j) {
        unsigned t0 = Tu[(size_t)crow[j] * 64 + lane];
        acc.x += __uint_as_float(t0 << 16); acc.y += __uint_as_float(t0 & 0xFFFF0000u);
    }

    acc.x *= dd; acc.y *= dd;
    if (!LAST) {
        float rx = fmaxf(acc.x + bias[2 * lane], 0.f);
        float ry = fmaxf(acc.y + bias[2 * lane + 1], 0.f);
        Anext[(size_t)node * 64 + lane] = (unsigned)f2bf(rx) | ((unsigned)f2bf(ry) << 16);
    } else {
        reinterpret_cast<float2*>(AGG)[(size_t)node * 64 + lane] = acc;
    }
}

// ---------------- pool (fused graph-boundary search): out[g] = sum/cnt + b3 ----------------

__global__ __launch_bounds__(128) void k_pool(const float* __restrict__ AGG, const float* __restrict__ b3,
                                              const int* __restrict__ batch, float* __restrict__ out) {
    int g = blockIdx.x;
    int c = threadIdx.x;
    int beg, end;
    { int lo = 0, hi = N_NODES; while (lo < hi) { int m = (lo + hi) >> 1; if (batch[m] < g) lo = m + 1; else hi = m; } beg = lo; }
    { int lo = beg, hi = N_NODES; while (lo < hi) { int m = (lo + hi) >> 1; if (batch[m] < g + 1) lo = m + 1; else hi = m; } end = lo; }
    float acc = 0.f;
    #pragma unroll 4
    for (int i = beg; i < end; ++i) acc += AGG[(size_t)i * D + c];
    int n = end - beg;
    out[g * D + c] = (acc + (float)n * b3[c]) / (float)(n > 0 ? n : 1);
}

// ---------------- launch ----------------

static inline size_t align256(size_t x) { return (x + 255) & ~(size_t)255; }

extern "C" void kernel_launch(void* const* d_in, const int* in_sizes, int n_in,
                              void* d_out, int out_size, void* d_ws, size_t ws_size,
                              hipStream_t stream) {
    const float* x    = (const float*)d_in[0];
    const int*  ei    = (const int*)d_in[1];
    const int*  batch = (const int*)d_in[2];
    const float* W1 = (const float*)d_in[3];
    const float* b1 = (const float*)d_in[4];
    const float* W2 = (const float*)d_in[5];
    const float* b2 = (const float*)d_in[6];
    const float* W3 = (const float*)d_in[7];
    const float* b3 = (const float*)d_in[8];
    float* out = (float*)d_out;

    char* ws = (char*)d_ws;
    size_t off = 0;
    auto alloc = [&](size_t bytes) { void* p = ws + off; off = align256(off + bytes); return p; };
    int*   cnt  = (int*)  alloc((size_t)N_NODES * 4);
    int*   col  = (int*)  alloc((size_t)N_NODES * CAP * 4);          // 12.8 MB
    unsigned short* Wp = (unsigned short*)alloc((size_t)3 * 32768 * 2);
    unsigned short* Ab = (unsigned short*)alloc((size_t)N_PAD * D * 2);
    unsigned short* T  = (unsigned short*)alloc((size_t)N_PAD * D * 2);
    float* AGG  = (float*)alloc((size_t)N_NODES * D * 4);
    (void)ws_size; (void)in_sizes; (void)n_in; (void)out_size;

    hipMemsetAsync(cnt, 0, (size_t)N_NODES * 4, stream);

    k_pack<<<(3 * D * D + 255) / 256, 256, 0, stream>>>(W1, W2, W3, Wp);
    k_fill<<<256, 256, 0, stream>>>(ei, cnt, col);

    const int agg_grid = (N_NODES + 3) / 4;

    k_mfma<true ><<<GEMM_GRID, 256, 0, stream>>>(x,  Wp,         cnt, T);
    k_agg<false><<<agg_grid, 256, 0, stream>>>((const unsigned*)T, nullptr, (unsigned*)Ab, b1, cnt, col);
    k_mfma<false><<<GEMM_GRID, 256, 0, stream>>>(Ab, Wp + 32768, cnt, T);
    k_agg<false><<<agg_grid, 256, 0, stream>>>((const unsigned*)T, nullptr, (unsigned*)Ab, b2, cnt, col);
    k_mfma<false><<<GEMM_GRID, 256, 0, stream>>>(Ab, Wp + 65536, cnt, T);
    k_agg<true ><<<agg_grid, 256, 0, stream>>>((const unsigned*)T, AGG, nullptr, nullptr, cnt, col);
    k_pool<<<N_GRAPHS, 128, 0, stream>>>(AGG, b3, batch, out);
}

// Round 9
// 293.803 us; speedup vs baseline: 1.1056x; 1.1056x over previous
//
#include <hip/hip_runtime.h>

#define N_NODES 50000
#define N_PAD   50048                    // padded rows (multiple of 64)
#define N_EDGES 800000
#define N_GRAPHS 256
#define D 128
#define CAP 64                           // fixed CSR row capacity (max in-degree ~45 for Poisson(16))
#define GEMM_GRID (N_PAD / 64)           // 782

#define NBUCK 196                        // node buckets of 256 (196*256 = 50176 >= N_NODES)
#define BCAP  4608                       // per-bucket edge capacity: mean 4096 + 8 sigma
#define EPB_I4 512                       // int4 per k_part block (2048 edges)
#define NBLK_A ((N_EDGES / 4 + EPB_I4 - 1) / EPB_I4)   // 391

typedef short bf16x8 __attribute__((ext_vector_type(8)));
typedef float f32x4  __attribute__((ext_vector_type(4)));

// bf16 helpers (bit-exact RNE convert)
__device__ inline unsigned short f2bf(float f) {
    unsigned u = __float_as_uint(f);
    u += 0x7FFF + ((u >> 16) & 1);
    return (unsigned short)(u >> 16);
}
__device__ inline float bf2f(unsigned short b) { return __uint_as_float((unsigned)b << 16); }

// ---------------- W pack: per-MFMA-fragment contiguous, hi/lo bf16 split ----------------
// layer layout: [frag f=(kt*8+nt)][lane][8] hi plane (16384 us), then lo plane (16384 us)
__global__ __launch_bounds__(256) void k_pack(const float* __restrict__ W1, const float* __restrict__ W2,
                                              const float* __restrict__ W3, unsigned short* __restrict__ Wp) {
    int idx = blockIdx.x * 256 + threadIdx.x;        // 3*16384
    if (idx >= 3 * D * D) return;
    int L = idx >> 14, rem = idx & 16383;
    int k = rem >> 7, n = rem & 127;
    const float* W = (L == 0) ? W1 : (L == 1) ? W2 : W3;
    float w = W[k * D + n];
    int kt = k >> 5, kg = (k >> 3) & 3, i = k & 7;
    int nt = n >> 4, ln = kg * 16 + (n & 15);
    size_t dst = (size_t)L * 32768 + ((size_t)(kt * 8 + nt) * 64 + ln) * 8 + i;
    unsigned short hi = f2bf(w);
    Wp[dst]         = hi;
    Wp[dst + 16384] = f2bf(w - bf2f(hi));            // residual
}

// ---------------- CSR build, pass A: LDS-radix partition by dst>>8 ----------------
// Per-edge work uses LDS atomics only; global atomics are one per (block, bucket) reserve
// (~77K total vs 800K random global atomics in R7/R8 — that chain was the 61us).
// Edge packed to 4B: (dst&255)<<16 | src  (src < 65536).

__global__ __launch_bounds__(256) void k_part(const int* __restrict__ ei, int* __restrict__ cursor,
                                              unsigned* __restrict__ buck) {
    __shared__ int hist[NBUCK];
    __shared__ int lbase[NBUCK];
    for (int i = threadIdx.x; i < NBUCK; i += 256) hist[i] = 0;
    __syncthreads();

    const int4* s4 = reinterpret_cast<const int4*>(ei);
    const int4* d4 = reinterpret_cast<const int4*>(ei + N_EDGES);
    int idx0 = blockIdx.x * EPB_I4 + threadIdx.x;
    int idx1 = idx0 + 256;
    bool v0 = idx0 < N_EDGES / 4, v1 = idx1 < N_EDGES / 4;
    int4 d0 = {}, d1 = {}, s0 = {}, s1 = {};
    if (v0) {
        d0 = d4[idx0]; s0 = s4[idx0];
        atomicAdd(&hist[d0.x >> 8], 1); atomicAdd(&hist[d0.y >> 8], 1);
        atomicAdd(&hist[d0.z >> 8], 1); atomicAdd(&hist[d0.w >> 8], 1);
    }
    if (v1) {
        d1 = d4[idx1]; s1 = s4[idx1];
        atomicAdd(&hist[d1.x >> 8], 1); atomicAdd(&hist[d1.y >> 8], 1);
        atomicAdd(&hist[d1.z >> 8], 1); atomicAdd(&hist[d1.w >> 8], 1);
    }
    __syncthreads();

    for (int i = threadIdx.x; i < NBUCK; i += 256)
        lbase[i] = atomicAdd(&cursor[i], hist[i]);   // reserve this block's runs
    __syncthreads();

    auto put = [&](int d, int s) {
        int b = d >> 8;
        int p = atomicAdd(&lbase[b], 1);             // LDS-allocated global slot
        if (p < BCAP) buck[(size_t)b * BCAP + p] = ((unsigned)(d & 255) << 16) | (unsigned)s;
    };
    if (v0) { put(d0.x, s0.x); put(d0.y, s0.y); put(d0.z, s0.z); put(d0.w, s0.w); }
    if (v1) { put(d1.x, s1.x); put(d1.y, s1.y); put(d1.z, s1.z); put(d1.w, s1.w); }
}

// ---------------- CSR build, pass B: per-bucket row construction ----------------
// One block per bucket; scatter region = 256 nodes * 128B = 32KB, single-XCD L2-resident.
// Also writes cnt coalesced (no cnt memset needed).

__global__ __launch_bounds__(256) void k_build(const unsigned* __restrict__ buck,
                                               const int* __restrict__ cursor,
                                               int* __restrict__ cnt, unsigned short* __restrict__ colu) {
    __shared__ int lcnt[256];
    int b = blockIdx.x;
    lcnt[threadIdx.x] = 0;
    __syncthreads();
    int nE = min(cursor[b], BCAP);
    const unsigned* bb = buck + (size_t)b * BCAP;
    for (int i = threadIdx.x; i < nE; i += 256) {
        unsigned v = bb[i];
        int dl = v >> 16, s = v & 0xFFFF;
        int p = atomicAdd(&lcnt[dl], 1);
        if (p < CAP) colu[(size_t)(b * 256 + dl) * CAP + p] = (unsigned short)s;
    }
    __syncthreads();
    int node = b * 256 + threadIdx.x;
    if (node < N_NODES) cnt[node] = lcnt[threadIdx.x];
}

// ---------------- MFMA GEMM: T'(bf16) = dinv_row * (A @ W)  (W hi/lo split, no LDS) ----------------
// wave = 16 rows x 128 cols; A-frag b128 direct from global

template<bool F32IN>
__global__ __launch_bounds__(256) void k_mfma(const void* __restrict__ Ain,
                                              const unsigned short* __restrict__ Wp,
                                              const int* __restrict__ cnt,
                                              unsigned short* __restrict__ T) {
    int l  = threadIdx.x & 63;
    int wv = threadIdx.x >> 6;
    int row0 = blockIdx.x * 64 + wv * 16;
    int arow = row0 + (l & 15);
    int kchunk = l >> 4;
    const uint4* wp4 = reinterpret_cast<const uint4*>(Wp);   // [frag*64+lane], lo at +2048

    f32x4 acc[8] = {};
    #pragma unroll
    for (int s = 0; s < 4; ++s) {                    // K steps of 32
        bf16x8 af;
        if (F32IN) {
            float4 a0 = {}, a1 = {};
            if (arow < N_NODES) {
                const float* xr = (const float*)Ain + (size_t)arow * D + s * 32 + kchunk * 8;
                a0 = reinterpret_cast<const float4*>(xr)[0];
                a1 = reinterpret_cast<const float4*>(xr)[1];
            }
            unsigned short h[8] = { f2bf(a0.x), f2bf(a0.y), f2bf(a0.z), f2bf(a0.w),
                                    f2bf(a1.x), f2bf(a1.y), f2bf(a1.z), f2bf(a1.w) };
            __builtin_memcpy(&af, h, 16);
        } else {
            const unsigned short* ar = (const unsigned short*)Ain + (size_t)arow * D;
            uint4 av = reinterpret_cast<const uint4*>(ar)[s * 4 + kchunk];
            __builtin_memcpy(&af, &av, 16);
        }
        #pragma unroll
        for (int nt = 0; nt < 8; ++nt) {
            int f = s * 8 + nt;
            uint4 bh = wp4[f * 64 + l];
            uint4 bl = wp4[f * 64 + l + 2048];
            bf16x8 bhf, blf;
            __builtin_memcpy(&bhf, &bh, 16);
            __builtin_memcpy(&blf, &bl, 16);
            acc[nt] = __builtin_amdgcn_mfma_f32_16x16x32_bf16(af, bhf, acc[nt], 0, 0, 0);
            acc[nt] = __builtin_amdgcn_mfma_f32_16x16x32_bf16(af, blf, acc[nt], 0, 0, 0);
        }
    }

    // C/D: col = lane&15, row = (lane>>4)*4 + reg   [m89-verified]
    int rbase = row0 + (l >> 4) * 4;
    int cr = l & 15;
    float sc[4];
    #pragma unroll
    for (int j = 0; j < 4; ++j) {
        int rr = rbase + j;
        sc[j] = (rr < N_NODES) ? rsqrtf((float)cnt[rr] + 1.f) : 0.f;   // dinv_row
    }
    #pragma unroll
    for (int nt = 0; nt < 8; ++nt)
        #pragma unroll
        for (int j = 0; j < 4; ++j) {
            int rr = rbase + j;
            if (rr < N_NODES) T[(size_t)rr * D + nt * 16 + cr] = f2bf(acc[nt][j] * sc[j]);
        }
}

// ---------------- pull aggregation: AGG[d] = dinv_d * (T'[d] + sum T'[col]) ----------------
// one wave per node; unweighted bf16-row sum, f32 accumulate; 8 gathers in flight per iter

template<bool LAST>
__global__ __launch_bounds__(256) void k_agg(const unsigned* __restrict__ Tu, float* __restrict__ AGG,
                                             unsigned* __restrict__ Anext, const float* __restrict__ bias,
                                             const int* __restrict__ cnt, const unsigned short* __restrict__ colu) {
    int node = blockIdx.x * 4 + (threadIdx.x >> 6);
    int lane = threadIdx.x & 63;
    if (node >= N_NODES) return;

    int len = cnt[node];
    float dd = rsqrtf((float)len + 1.f);
    unsigned ts = Tu[(size_t)node * 64 + lane];
    float2 acc;
    acc.x = __uint_as_float(ts << 16);               // low bf16 = even col
    acc.y = __uint_as_float(ts & 0xFFFF0000u);       // high bf16 = odd col

    const unsigned short* crow = colu + (size_t)node * CAP;   // 128B-aligned row
    int j = 0;
    for (; j + 8 <= len; j += 8) {
        uint4 c = *reinterpret_cast<const uint4*>(crow + j);  // 8 ushort srcs
        int s0 = c.x & 0xFFFF, s1 = c.x >> 16;
        int s2 = c.y & 0xFFFF, s3 = c.y >> 16;
        int s4 = c.z & 0xFFFF, s5 = c.z >> 16;
        int s6 = c.w & 0xFFFF, s7 = c.w >> 16;
        unsigned t0 = Tu[(size_t)s0 * 64 + lane];
        unsigned t1 = Tu[(size_t)s1 * 64 + lane];
        unsigned t2 = Tu[(size_t)s2 * 64 + lane];
        unsigned t3 = Tu[(size_t)s3 * 64 + lane];
        unsigned t4 = Tu[(size_t)s4 * 64 + lane];
        unsigned t5 = Tu[(size_t)s5 * 64 + lane];
        unsigned t6 = Tu[(size_t)s6 * 64 + lane];
        unsigned t7 = Tu[(size_t)s7 * 64 + lane];
        acc.x += __uint_as_float(t0 << 16); acc.y += __uint_as_float(t0 & 0xFFFF0000u);
        acc.x += __uint_as_float(t1 << 16); acc.y += __uint_as_float(t1 & 0xFFFF0000u);
        acc.x += __uint_as_float(t2 << 16); acc.y += __uint_as_float(t2 & 0xFFFF0000u);
        acc.x += __uint_as_float(t3 << 16); acc.y += __uint_as_float(t3 & 0xFFFF0000u);
        acc.x += __uint_as_float(t4 << 16); acc.y += __uint_as_float(t4 & 0xFFFF0000u);
        acc.x += __uint_as_float(t5 << 16); acc.y += __uint_as_float(t5 & 0xFFFF0000u);
        acc.x += __uint_as_float(t6 << 16); acc.y += __uint_as_float(t6 & 0xFFFF0000u);
        acc.x += __uint_as_float(t7 << 16); acc.y += __uint_as_float(t7 & 0xFFFF0000u);
    }
    for (; j < len; ++j) {
        int s = crow[j];
        unsigned t0 = Tu[(size_t)s * 64 + lane];
        acc.x += __uint_as_float(t0 << 16); acc.y += __uint_as_float(t0 & 0xFFFF0000u);
    }

    acc.x *= dd; acc.y *= dd;
    if (!LAST) {
        float rx = fmaxf(acc.x + bias[2 * lane], 0.f);
        float ry = fmaxf(acc.y + bias[2 * lane + 1], 0.f);
        Anext[(size_t)node * 64 + lane] = (unsigned)f2bf(rx) | ((unsigned)f2bf(ry) << 16);
    } else {
        reinterpret_cast<float2*>(AGG)[(size_t)node * 64 + lane] = acc;
    }
}

// ---------------- pool (fused graph-boundary search): out[g] = sum/cnt + b3 ----------------

__global__ __launch_bounds__(128) void k_pool(const float* __restrict__ AGG, const float* __restrict__ b3,
                                              const int* __restrict__ batch, float* __restrict__ out) {
    int g = blockIdx.x;
    int c = threadIdx.x;
    int beg, end;
    { int lo = 0, hi = N_NODES; while (lo < hi) { int m = (lo + hi) >> 1; if (batch[m] < g) lo = m + 1; else hi = m; } beg = lo; }
    { int lo = beg, hi = N_NODES; while (lo < hi) { int m = (lo + hi) >> 1; if (batch[m] < g + 1) lo = m + 1; else hi = m; } end = lo; }
    float acc = 0.f;
    #pragma unroll 4
    for (int i = beg; i < end; ++i) acc += AGG[(size_t)i * D + c];
    int n = end - beg;
    out[g * D + c] = (acc + (float)n * b3[c]) / (float)(n > 0 ? n : 1);
}

// ---------------- launch ----------------

static inline size_t align256(size_t x) { return (x + 255) & ~(size_t)255; }

extern "C" void kernel_launch(void* const* d_in, const int* in_sizes, int n_in,
                              void* d_out, int out_size, void* d_ws, size_t ws_size,
                              hipStream_t stream) {
    const float* x    = (const float*)d_in[0];
    const int*  ei    = (const int*)d_in[1];
    const int*  batch = (const int*)d_in[2];
    const float* W1 = (const float*)d_in[3];
    const float* b1 = (const float*)d_in[4];
    const float* W2 = (const float*)d_in[5];
    const float* b2 = (const float*)d_in[6];
    const float* W3 = (const float*)d_in[7];
    const float* b3 = (const float*)d_in[8];
    float* out = (float*)d_out;

    char* ws = (char*)d_ws;
    size_t off = 0;
    auto alloc = [&](size_t bytes) { void* p = ws + off; off = align256(off + bytes); return p; };
    int*      cursor = (int*)     alloc((size_t)NBUCK * 4);
    unsigned* buck   = (unsigned*)alloc((size_t)NBUCK * BCAP * 4);        // 3.6 MB
    int*      cnt    = (int*)     alloc((size_t)N_NODES * 4);
    unsigned short* colu = (unsigned short*)alloc((size_t)NBUCK * 256 * CAP * 2);  // 6.4 MB
    unsigned short* Wp = (unsigned short*)alloc((size_t)3 * 32768 * 2);
    unsigned short* Ab = (unsigned short*)alloc((size_t)N_PAD * D * 2);
    unsigned short* T  = (unsigned short*)alloc((size_t)N_PAD * D * 2);
    float* AGG  = (float*)alloc((size_t)N_NODES * D * 4);
    (void)ws_size; (void)in_sizes; (void)n_in; (void)out_size;

    hipMemsetAsync(cursor, 0, (size_t)NBUCK * 4, stream);

    k_pack <<<(3 * D * D + 255) / 256, 256, 0, stream>>>(W1, W2, W3, Wp);
    k_part <<<NBLK_A, 256, 0, stream>>>(ei, cursor, buck);
    k_build<<<NBUCK, 256, 0, stream>>>(buck, cursor, cnt, colu);

    const int agg_grid = (N_NODES + 3) / 4;

    k_mfma<true ><<<GEMM_GRID, 256, 0, stream>>>(x,  Wp,         cnt, T);
    k_agg<false><<<agg_grid, 256, 0, stream>>>((const unsigned*)T, nullptr, (unsigned*)Ab, b1, cnt, colu);
    k_mfma<false><<<GEMM_GRID, 256, 0, stream>>>(Ab, Wp + 32768, cnt, T);
    k_agg<false><<<agg_grid, 256, 0, stream>>>((const unsigned*)T, nullptr, (unsigned*)Ab, b2, cnt, colu);
    k_mfma<false><<<GEMM_GRID, 256, 0, stream>>>(Ab, Wp + 65536, cnt, T);
    k_agg<true ><<<agg_grid, 256, 0, stream>>>((const unsigned*)T, AGG, nullptr, nullptr, cnt, colu);
    k_pool <<<N_GRAPHS, 128, 0, stream>>>(AGG, b3, batch, out);
}

// Round 10
// 276.338 us; speedup vs baseline: 1.1755x; 1.0632x over previous
//
#include <hip/hip_runtime.h>

#define N_NODES 50000
#define N_PAD   50048                    // padded rows (multiple of 128)
#define N_EDGES 800000
#define N_GRAPHS 256
#define D 128
#define CAP 64                           // fixed CSR row capacity (max in-degree ~45 for Poisson(16))
#define MFMA_GRID (N_PAD / 128)          // 391 blocks x 8 waves x 16 rows

#define NBUCK 196                        // node buckets of 256 (196*256 = 50176 >= N_NODES)
#define BCAP  4608                       // per-bucket edge capacity: mean 4096 + 8 sigma
#define EPB_I4 512                       // int4 per k_part block (2048 edges)
#define NBLK_A ((N_EDGES / 4 + EPB_I4 - 1) / EPB_I4)   // 391

typedef short bf16x8 __attribute__((ext_vector_type(8)));
typedef float f32x4  __attribute__((ext_vector_type(4)));

// bf16 helpers (bit-exact RNE convert)
__device__ inline unsigned short f2bf(float f) {
    unsigned u = __float_as_uint(f);
    u += 0x7FFF + ((u >> 16) & 1);
    return (unsigned short)(u >> 16);
}
__device__ inline float bf2f(unsigned short b) { return __uint_as_float((unsigned)b << 16); }

// ---------------- W pack: per-MFMA-fragment contiguous, hi/lo bf16 split ----------------
// layer layout: [frag f=(kt*8+nt)][lane][8] hi plane (16384 us), then lo plane (16384 us)
__global__ __launch_bounds__(256) void k_pack(const float* __restrict__ W1, const float* __restrict__ W2,
                                              const float* __restrict__ W3, unsigned short* __restrict__ Wp) {
    int idx = blockIdx.x * 256 + threadIdx.x;        // 3*16384
    if (idx >= 3 * D * D) return;
    int L = idx >> 14, rem = idx & 16383;
    int k = rem >> 7, n = rem & 127;
    const float* W = (L == 0) ? W1 : (L == 1) ? W2 : W3;
    float w = W[k * D + n];
    int kt = k >> 5, kg = (k >> 3) & 3, i = k & 7;
    int nt = n >> 4, ln = kg * 16 + (n & 15);
    size_t dst = (size_t)L * 32768 + ((size_t)(kt * 8 + nt) * 64 + ln) * 8 + i;
    unsigned short hi = f2bf(w);
    Wp[dst]         = hi;
    Wp[dst + 16384] = f2bf(w - bf2f(hi));            // residual
}

// ---------------- CSR build, pass A: LDS-radix partition by dst>>8 ----------------
// Per-edge work uses LDS atomics only; global atomics are one per (block, bucket) reserve.
// Edge packed to 4B: (dst&255)<<16 | src  (src < 65536).

__global__ __launch_bounds__(256) void k_part(const int* __restrict__ ei, int* __restrict__ cursor,
                                              unsigned* __restrict__ buck) {
    __shared__ int hist[NBUCK];
    __shared__ int lbase[NBUCK];
    for (int i = threadIdx.x; i < NBUCK; i += 256) hist[i] = 0;
    __syncthreads();

    const int4* s4 = reinterpret_cast<const int4*>(ei);
    const int4* d4 = reinterpret_cast<const int4*>(ei + N_EDGES);
    int idx0 = blockIdx.x * EPB_I4 + threadIdx.x;
    int idx1 = idx0 + 256;
    bool v0 = idx0 < N_EDGES / 4, v1 = idx1 < N_EDGES / 4;
    int4 d0 = {}, d1 = {}, s0 = {}, s1 = {};
    if (v0) {
        d0 = d4[idx0]; s0 = s4[idx0];
        atomicAdd(&hist[d0.x >> 8], 1); atomicAdd(&hist[d0.y >> 8], 1);
        atomicAdd(&hist[d0.z >> 8], 1); atomicAdd(&hist[d0.w >> 8], 1);
    }
    if (v1) {
        d1 = d4[idx1]; s1 = s4[idx1];
        atomicAdd(&hist[d1.x >> 8], 1); atomicAdd(&hist[d1.y >> 8], 1);
        atomicAdd(&hist[d1.z >> 8], 1); atomicAdd(&hist[d1.w >> 8], 1);
    }
    __syncthreads();

    for (int i = threadIdx.x; i < NBUCK; i += 256)
        lbase[i] = atomicAdd(&cursor[i], hist[i]);   // reserve this block's runs
    __syncthreads();

    auto put = [&](int d, int s) {
        int b = d >> 8;
        int p = atomicAdd(&lbase[b], 1);             // LDS-allocated global slot
        if (p < BCAP) buck[(size_t)b * BCAP + p] = ((unsigned)(d & 255) << 16) | (unsigned)s;
    };
    if (v0) { put(d0.x, s0.x); put(d0.y, s0.y); put(d0.z, s0.z); put(d0.w, s0.w); }
    if (v1) { put(d1.x, s1.x); put(d1.y, s1.y); put(d1.z, s1.z); put(d1.w, s1.w); }
}

// ---------------- CSR build, pass B: per-bucket row construction ----------------

__global__ __launch_bounds__(256) void k_build(const unsigned* __restrict__ buck,
                                               const int* __restrict__ cursor,
                                               int* __restrict__ cnt, unsigned short* __restrict__ colu) {
    __shared__ int lcnt[256];
    int b = blockIdx.x;
    lcnt[threadIdx.x] = 0;
    __syncthreads();
    int nE = min(cursor[b], BCAP);
    const unsigned* bb = buck + (size_t)b * BCAP;
    for (int i = threadIdx.x; i < nE; i += 256) {
        unsigned v = bb[i];
        int dl = v >> 16, s = v & 0xFFFF;
        int p = atomicAdd(&lcnt[dl], 1);
        if (p < CAP) colu[(size_t)(b * 256 + dl) * CAP + p] = (unsigned short)s;
    }
    __syncthreads();
    int node = b * 256 + threadIdx.x;
    if (node < N_NODES) cnt[node] = lcnt[threadIdx.x];
}

// ---------------- MFMA GEMM: T'(bf16) = dinv_row * (A @ W) ----------------
// W (hi+lo planes, 64KB) staged once per block in LDS; 8 waves x 16 rows each.
// Old version re-read 64KB of W from global PER WAVE (~200MB L2 traffic/layer) — that, not
// the math (0.4us), was the cost. ds_read stride-1 b128 is bank-conflict-free.

template<bool F32IN>
__global__ __launch_bounds__(512) void k_mfma(const void* __restrict__ Ain,
                                              const unsigned short* __restrict__ Wp,
                                              const int* __restrict__ cnt,
                                              unsigned short* __restrict__ T) {
    __shared__ uint4 Wl[4096];                       // 64KB: hi [0,2048), lo [2048,4096)
    const uint4* wp4 = reinterpret_cast<const uint4*>(Wp);
    for (int i = threadIdx.x; i < 4096; i += 512) Wl[i] = wp4[i];
    __syncthreads();

    int l  = threadIdx.x & 63;
    int wv = threadIdx.x >> 6;                       // 0..7
    int row0 = blockIdx.x * 128 + wv * 16;
    int arow = row0 + (l & 15);
    int kchunk = l >> 4;

    f32x4 acc[8] = {};
    #pragma unroll
    for (int s = 0; s < 4; ++s) {                    // K steps of 32
        bf16x8 af;
        if (F32IN) {
            float4 a0 = {}, a1 = {};
            if (arow < N_NODES) {
                const float* xr = (const float*)Ain + (size_t)arow * D + s * 32 + kchunk * 8;
                a0 = reinterpret_cast<const float4*>(xr)[0];
                a1 = reinterpret_cast<const float4*>(xr)[1];
            }
            unsigned short h[8] = { f2bf(a0.x), f2bf(a0.y), f2bf(a0.z), f2bf(a0.w),
                                    f2bf(a1.x), f2bf(a1.y), f2bf(a1.z), f2bf(a1.w) };
            __builtin_memcpy(&af, h, 16);
        } else {
            const unsigned short* ar = (const unsigned short*)Ain + (size_t)arow * D;
            uint4 av = reinterpret_cast<const uint4*>(ar)[s * 4 + kchunk];
            __builtin_memcpy(&af, &av, 16);
        }
        #pragma unroll
        for (int nt = 0; nt < 8; ++nt) {
            int f = s * 8 + nt;
            uint4 bh = Wl[f * 64 + l];
            uint4 bl = Wl[f * 64 + l + 2048];
            bf16x8 bhf, blf;
            __builtin_memcpy(&bhf, &bh, 16);
            __builtin_memcpy(&blf, &bl, 16);
            acc[nt] = __builtin_amdgcn_mfma_f32_16x16x32_bf16(af, bhf, acc[nt], 0, 0, 0);
            acc[nt] = __builtin_amdgcn_mfma_f32_16x16x32_bf16(af, blf, acc[nt], 0, 0, 0);
        }
    }

    // C/D: col = lane&15, row = (lane>>4)*4 + reg   [m89-verified]
    int rbase = row0 + (l >> 4) * 4;
    int cr = l & 15;
    float sc[4];
    #pragma unroll
    for (int j = 0; j < 4; ++j) {
        int rr = rbase + j;
        sc[j] = (rr < N_NODES) ? rsqrtf((float)cnt[rr] + 1.f) : 0.f;   // dinv_row
    }
    #pragma unroll
    for (int nt = 0; nt < 8; ++nt)
        #pragma unroll
        for (int j = 0; j < 4; ++j) {
            int rr = rbase + j;
            if (rr < N_NODES) T[(size_t)rr * D + nt * 16 + cr] = f2bf(acc[nt][j] * sc[j]);
        }
}

// ---------------- pull aggregation: AGG[d] = dinv_d * (T'[d] + sum T'[col]) ----------------
// one wave per node; unweighted bf16-row sum, f32 accumulate; 8 gathers in flight per iter.
// Output always packed bf16 (LAST: no bias/relu) — halves pool traffic too.

template<bool LAST>
__global__ __launch_bounds__(256) void k_agg(const unsigned* __restrict__ Tu,
                                             unsigned* __restrict__ Anext, const float* __restrict__ bias,
                                             const int* __restrict__ cnt, const unsigned short* __restrict__ colu) {
    int node = blockIdx.x * 4 + (threadIdx.x >> 6);
    int lane = threadIdx.x & 63;
    if (node >= N_NODES) return;

    int len = cnt[node];
    float dd = rsqrtf((float)len + 1.f);
    unsigned ts = Tu[(size_t)node * 64 + lane];
    float2 acc;
    acc.x = __uint_as_float(ts << 16);               // low bf16 = even col
    acc.y = __uint_as_float(ts & 0xFFFF0000u);       // high bf16 = odd col

    const unsigned short* crow = colu + (size_t)node * CAP;   // 128B-aligned row
    int j = 0;
    for (; j + 8 <= len; j += 8) {
        uint4 c = *reinterpret_cast<const uint4*>(crow + j);  // 8 ushort srcs
        int s0 = c.x & 0xFFFF, s1 = c.x >> 16;
        int s2 = c.y & 0xFFFF, s3 = c.y >> 16;
        int s4 = c.z & 0xFFFF, s5 = c.z >> 16;
        int s6 = c.w & 0xFFFF, s7 = c.w >> 16;
        unsigned t0 = Tu[(size_t)s0 * 64 + lane];
        unsigned t1 = Tu[(size_t)s1 * 64 + lane];
        unsigned t2 = Tu[(size_t)s2 * 64 + lane];
        unsigned t3 = Tu[(size_t)s3 * 64 + lane];
        unsigned t4 = Tu[(size_t)s4 * 64 + lane];
        unsigned t5 = Tu[(size_t)s5 * 64 + lane];
        unsigned t6 = Tu[(size_t)s6 * 64 + lane];
        unsigned t7 = Tu[(size_t)s7 * 64 + lane];
        acc.x += __uint_as_float(t0 << 16); acc.y += __uint_as_float(t0 & 0xFFFF0000u);
        acc.x += __uint_as_float(t1 << 16); acc.y += __uint_as_float(t1 & 0xFFFF0000u);
        acc.x += __uint_as_float(t2 << 16); acc.y += __uint_as_float(t2 & 0xFFFF0000u);
        acc.x += __uint_as_float(t3 << 16); acc.y += __uint_as_float(t3 & 0xFFFF0000u);
        acc.x += __uint_as_float(t4 << 16); acc.y += __uint_as_float(t4 & 0xFFFF0000u);
        acc.x += __uint_as_float(t5 << 16); acc.y += __uint_as_float(t5 & 0xFFFF0000u);
        acc.x += __uint_as_float(t6 << 16); acc.y += __uint_as_float(t6 & 0xFFFF0000u);
        acc.x += __uint_as_float(t7 << 16); acc.y += __uint_as_float(t7 & 0xFFFF0000u);
    }
    for (; j < len; ++j) {
        int s = crow[j];
        unsigned t0 = Tu[(size_t)s * 64 + lane];
        acc.x += __uint_as_float(t0 << 16); acc.y += __uint_as_float(t0 & 0xFFFF0000u);
    }

    acc.x *= dd; acc.y *= dd;
    if (!LAST) {
        acc.x = fmaxf(acc.x + bias[2 * lane], 0.f);
        acc.y = fmaxf(acc.y + bias[2 * lane + 1], 0.f);
    }
    Anext[(size_t)node * 64 + lane] = (unsigned)f2bf(acc.x) | ((unsigned)f2bf(acc.y) << 16);
}

// ---------------- pool (fused graph-boundary search): out[g] = sum(bf16 agg)/n + b3 ----------------

__global__ __launch_bounds__(128) void k_pool(const unsigned short* __restrict__ AGGb,
                                              const float* __restrict__ b3,
                                              const int* __restrict__ batch, float* __restrict__ out) {
    int g = blockIdx.x;
    int c = threadIdx.x;
    int beg, end;
    { int lo = 0, hi = N_NODES; while (lo < hi) { int m = (lo + hi) >> 1; if (batch[m] < g) lo = m + 1; else hi = m; } beg = lo; }
    { int lo = beg, hi = N_NODES; while (lo < hi) { int m = (lo + hi) >> 1; if (batch[m] < g + 1) lo = m + 1; else hi = m; } end = lo; }
    float acc = 0.f;
    #pragma unroll 4
    for (int i = beg; i < end; ++i) acc += bf2f(AGGb[(size_t)i * D + c]);
    int n = end - beg;
    out[g * D + c] = (acc + (float)n * b3[c]) / (float)(n > 0 ? n : 1);
}

// ---------------- launch ----------------

static inline size_t align256(size_t x) { return (x + 255) & ~(size_t)255; }

extern "C" void kernel_launch(void* const* d_in, const int* in_sizes, int n_in,
                              void* d_out, int out_size, void* d_ws, size_t ws_size,
                              hipStream_t stream) {
    const float* x    = (const float*)d_in[0];
    const int*  ei    = (const int*)d_in[1];
    const int*  batch = (const int*)d_in[2];
    const float* W1 = (const float*)d_in[3];
    const float* b1 = (const float*)d_in[4];
    const float* W2 = (const float*)d_in[5];
    const float* b2 = (const float*)d_in[6];
    const float* W3 = (const float*)d_in[7];
    const float* b3 = (const float*)d_in[8];
    float* out = (float*)d_out;

    char* ws = (char*)d_ws;
    size_t off = 0;
    auto alloc = [&](size_t bytes) { void* p = ws + off; off = align256(off + bytes); return p; };
    int*      cursor = (int*)     alloc((size_t)NBUCK * 4);
    unsigned* buck   = (unsigned*)alloc((size_t)NBUCK * BCAP * 4);        // 3.6 MB
    int*      cnt    = (int*)     alloc((size_t)N_NODES * 4);
    unsigned short* colu = (unsigned short*)alloc((size_t)NBUCK * 256 * CAP * 2);  // 6.4 MB
    unsigned short* Wp = (unsigned short*)alloc((size_t)3 * 32768 * 2);
    unsigned short* Ab = (unsigned short*)alloc((size_t)N_PAD * D * 2);
    unsigned short* T  = (unsigned short*)alloc((size_t)N_PAD * D * 2);
    (void)ws_size; (void)in_sizes; (void)n_in; (void)out_size;

    hipMemsetAsync(cursor, 0, (size_t)NBUCK * 4, stream);

    k_pack <<<(3 * D * D + 255) / 256, 256, 0, stream>>>(W1, W2, W3, Wp);
    k_part <<<NBLK_A, 256, 0, stream>>>(ei, cursor, buck);
    k_build<<<NBUCK, 256, 0, stream>>>(buck, cursor, cnt, colu);

    const int agg_grid = (N_NODES + 3) / 4;

    k_mfma<true ><<<MFMA_GRID, 512, 0, stream>>>(x,  Wp,         cnt, T);
    k_agg<false><<<agg_grid, 256, 0, stream>>>((const unsigned*)T, (unsigned*)Ab, b1, cnt, colu);
    k_mfma<false><<<MFMA_GRID, 512, 0, stream>>>(Ab, Wp + 32768, cnt, T);
    k_agg<false><<<agg_grid, 256, 0, stream>>>((const unsigned*)T, (unsigned*)Ab, b2, cnt, colu);
    k_mfma<false><<<MFMA_GRID, 512, 0, stream>>>(Ab, Wp + 65536, cnt, T);
    k_agg<true ><<<agg_grid, 256, 0, stream>>>((const unsigned*)T, (unsigned*)Ab, nullptr, cnt, colu);
    k_pool <<<N_GRAPHS, 128, 0, stream>>>(Ab, b3, batch, out);
}